// Round 1
// baseline (4467.847 us; speedup 1.0000x reference)
//
#include <hip/hip_runtime.h>
#include <math.h>

typedef short s8v __attribute__((ext_vector_type(8)));
typedef __bf16 bf8 __attribute__((ext_vector_type(8)));
typedef float f4v __attribute__((ext_vector_type(4)));

#define DEV static __device__ __forceinline__

DEV ushort f2bf(float f){
  union { float f; unsigned u; } v; v.f = f;
  unsigned u = v.u;
  return (ushort)((u + 0x7fffu + ((u>>16)&1u)) >> 16);
}
DEV float bf2f(ushort u){
  union { unsigned u; float f; } v; v.u = ((unsigned)u)<<16; return v.f;
}
DEV float sigm(float x){ return 1.0f/(1.0f + __expf(-x)); }
DEV float wred(float x){
  #pragma unroll
  for(int off=32; off; off>>=1) x += __shfl_xor(x, off, 64);
  return x;
}

// ---------------- cast / build kernels (precompute) ----------------

__global__ void k_cast(const float* __restrict__ s, ushort* __restrict__ d, long n4){
  long i = (long)blockIdx.x*256 + threadIdx.x;
  const long st = (long)gridDim.x*256;
  for(; i<n4; i+=st){
    float4 v = ((const float4*)s)[i];
    ushort4 o; o.x=f2bf(v.x); o.y=f2bf(v.y); o.z=f2bf(v.z); o.w=f2bf(v.w);
    ((ushort4*)d)[i]=o;
  }
}

// Wcat[2048][4096]: rows 0:1024 = W_ih rows 2048:3072 ; rows 1024:2048 = W_hh
__global__ void k_wcat(const float* __restrict__ wih, const float* __restrict__ whh, ushort* __restrict__ dst){
  long i = (long)blockIdx.x*256 + threadIdx.x;
  const long st = (long)gridDim.x*256;
  const long n4 = 2048L*4096/4;
  for(; i<n4; i+=st){
    long pos = i*4; int row = (int)(pos>>12); int col = (int)(pos&4095);
    const float* s = (row<1024) ? (wih + ((long)(2048+row)<<12) + col)
                                : (whh + ((long)(row-1024)<<12) + col);
    float4 v = *(const float4*)s;
    ushort4 o; o.x=f2bf(v.x); o.y=f2bf(v.y); o.z=f2bf(v.z); o.w=f2bf(v.w);
    *(ushort4*)&dst[pos] = o;
  }
}

// Bcat[1024][3072] = [W_col | W_tab | W_act] (bf16)
__global__ void k_bcat(const float* __restrict__ Wc, const float* __restrict__ Wt,
                       const float* __restrict__ Wa, ushort* __restrict__ dst){
  long i = (long)blockIdx.x*256 + threadIdx.x;
  const long st = (long)gridDim.x*256;
  const long n4 = 1024L*3072/4;
  for(; i<n4; i+=st){
    long pos = i*4; int row = (int)(pos/3072); int col = (int)(pos - (long)row*3072);
    const float* s;
    if(col<1024) s = Wc + ((long)row<<10) + col;
    else if(col<2048) s = Wt + ((long)row<<10) + (col-1024);
    else s = Wa + ((long)row<<10) + (col-2048);
    float4 v = *(const float4*)s;
    ushort4 o; o.x=f2bf(v.x); o.y=f2bf(v.y); o.z=f2bf(v.z); o.w=f2bf(v.w);
    *(ushort4*)&dst[pos] = o;
  }
}

// P[2560][2048] bf16: cols 0:1024 = prev_emb(t), cols 1024:2048 = node_emb(t)
__global__ void k_gatherP(const float* __restrict__ emba, const float* __restrict__ ecol,
                          const float* __restrict__ etab, const float* __restrict__ symb,
                          const int* __restrict__ kindv, const int* __restrict__ gold,
                          const int* __restrict__ cur, ushort* __restrict__ P){
  long i = (long)blockIdx.x*256 + threadIdx.x;
  const long st = (long)gridDim.x*256;
  const long n4 = 2560L*2048/4;
  for(; i<n4; i+=st){
    long pos = i*4; int row = (int)(pos>>11); int col = (int)(pos&2047);
    int t = row>>6, b = row&63;
    ushort4 o;
    if(col < 1024){
      if(t==0){ o.x=o.y=o.z=o.w=0; *(ushort4*)&P[pos]=o; continue; }
      int k = kindv[(t-1)*64+b];
      int gi = gold[(t-1)*64+b];
      const float* s;
      if(k==0) s = emba + ((long)(gi & 127))*1024 + col;
      else if(k==1) s = ecol + (((long)b<<6) + (gi & 63))*1024 + col;
      else s = etab + (((long)b<<5) + (gi & 31))*1024 + col;
      float4 v = *(const float4*)s;
      o.x=f2bf(v.x); o.y=f2bf(v.y); o.z=f2bf(v.z); o.w=f2bf(v.w);
    } else {
      const float* s = symb + ((long)cur[t*64+b])*1024 + (col-1024);
      float4 v = *(const float4*)s;
      o.x=f2bf(v.x); o.y=f2bf(v.y); o.z=f2bf(v.z); o.w=f2bf(v.w);
    }
    *(ushort4*)&P[pos] = o;
  }
}

__global__ void k_init(const float* __restrict__ h0, const float* __restrict__ c0,
                       const float* __restrict__ bih, const float* __restrict__ bhh,
                       float* __restrict__ hb, float* __restrict__ cbuf,
                       float* __restrict__ biasvec, float* __restrict__ out){
  int i = blockIdx.x*256 + threadIdx.x;
  if(i < 65536){ hb[i]=h0[i]; cbuf[i]=c0[i]; }
  if(i < 4096) biasvec[i] = bih[i] + bhh[i];
  if(i < 64) out[i] = 0.f;
}

// vv[3][1024]: b_out@W_act+b_act, b_out@W_col+b_col, b_out@W_tab+b_tab
__global__ void k_bias1(const float* __restrict__ bout,
                        const float* __restrict__ Wa, const float* __restrict__ ba,
                        const float* __restrict__ Wc, const float* __restrict__ bc,
                        const float* __restrict__ Wt, const float* __restrict__ bt,
                        float* __restrict__ vv){
  int j = blockIdx.x*256 + threadIdx.x;
  if(j >= 3072) return;
  int which = j>>10, col = j&1023;
  const float* W = (which==0)?Wa:(which==1)?Wc:Wt;
  const float* bb = (which==0)?ba:(which==1)?bc:bt;
  float s = bb[col];
  for(int i=0;i<1024;i++) s += bout[i]*W[((long)i<<10)+col];
  vv[j] = s;
}

// dbuf[6272]: dots of vv with emb rows / e_col rows / e_tab rows
__global__ void k_bias2a(const float* __restrict__ vv, const float* __restrict__ emb,
                         const float* __restrict__ ecol, const float* __restrict__ etab,
                         float* __restrict__ dbuf){
  int wid = blockIdx.x*4 + (threadIdx.x>>6);
  int l = threadIdx.x & 63;
  if(wid >= 6272) return;
  const float* src; const float* v;
  if(wid < 128){ src = emb + ((long)wid<<10); v = vv; }
  else if(wid < 4224){ src = ecol + ((long)(wid-128)<<10); v = vv+1024; }
  else { src = etab + ((long)(wid-4224)<<10); v = vv+2048; }
  const float* sp = src + l*16; const float* vp = v + l*16;
  float s = 0.f;
  #pragma unroll
  for(int i=0;i<16;i+=4){
    float4 a = *(const float4*)(sp+i); float4 bvv = *(const float4*)(vp+i);
    s += a.x*bvv.x + a.y*bvv.y + a.z*bvv.z + a.w*bvv.w;
  }
  s = wred(s);
  if(l==0) dbuf[wid] = s;
}

__global__ void k_bias2b(const float* __restrict__ dbuf,
                         const int* __restrict__ amask, const int* __restrict__ cmask,
                         const int* __restrict__ tmask,
                         float* __restrict__ ca, float* __restrict__ cb, float* __restrict__ ct){
  int i = blockIdx.x*256 + threadIdx.x;
  if(i < 8192){ ca[i] = dbuf[i&127] + ((amask[i]==1)?-1.0e9f:0.f); }
  else if(i < 12288){ int j=i-8192; cb[j] = dbuf[128+j] + ((cmask[j]==1)?-1.0e9f:0.f); }
  else if(i < 14336){ int j=i-12288; ct[j] = dbuf[4224+j] + ((tmask[j]==1)?-1.0e9f:0.f); }
}

// ---------------- generic bf16 MFMA GEMM (64x64 tile, 4 waves) ----------------
// C[M,N] = A[M,K] @ B[K,N] (+bias).  A: f32 or bf16 row-major.  B: bf16;
// BCOL means B[k][n] = Bp[n*ldb + k] (source row-major [N][K]).
template<bool AF32, bool BCOL, bool OBF16, bool HASB>
__global__ __launch_bounds__(256) void k_gemm(const void* __restrict__ Ap,
    const ushort* __restrict__ Bp, void* __restrict__ Cp, const float* __restrict__ bias,
    int M, int N, int K, int lda, int ldb, int ldc, long sAz, long sCz)
{
  __shared__ ushort As[64][72];
  __shared__ ushort Bs[64][72];
  const int tid = threadIdx.x;
  const int w = tid>>6, l = tid&63;
  const int r = tid>>2, cc = (tid&3)<<4;
  const int m0 = blockIdx.y<<6, n0 = blockIdx.x<<6;
  const int z = blockIdx.z;

  f4v acc[4];
  #pragma unroll
  for(int i=0;i<4;i++) acc[i] = (f4v){0.f,0.f,0.f,0.f};

  for(int k0=0; k0<K; k0+=64){
    { // stage A
      const int gm = m0 + r;
      ushort* dst = &As[r][cc];
      if(gm < M){
        if constexpr(AF32){
          const float* a = (const float*)Ap + sAz*z + (long)gm*lda + k0 + cc;
          float4 v0=*(const float4*)(a), v1=*(const float4*)(a+4), v2=*(const float4*)(a+8), v3=*(const float4*)(a+12);
          s8v o0, o1;
          o0[0]=(short)f2bf(v0.x); o0[1]=(short)f2bf(v0.y); o0[2]=(short)f2bf(v0.z); o0[3]=(short)f2bf(v0.w);
          o0[4]=(short)f2bf(v1.x); o0[5]=(short)f2bf(v1.y); o0[6]=(short)f2bf(v1.z); o0[7]=(short)f2bf(v1.w);
          o1[0]=(short)f2bf(v2.x); o1[1]=(short)f2bf(v2.y); o1[2]=(short)f2bf(v2.z); o1[3]=(short)f2bf(v2.w);
          o1[4]=(short)f2bf(v3.x); o1[5]=(short)f2bf(v3.y); o1[6]=(short)f2bf(v3.z); o1[7]=(short)f2bf(v3.w);
          *(s8v*)dst = o0; *(s8v*)(dst+8) = o1;
        } else {
          const ushort* a = (const ushort*)Ap + sAz*z + (long)gm*lda + k0 + cc;
          *(s8v*)dst = *(const s8v*)a; *(s8v*)(dst+8) = *(const s8v*)(a+8);
        }
      } else {
        s8v zz = (s8v){0,0,0,0,0,0,0,0};
        *(s8v*)dst = zz; *(s8v*)(dst+8) = zz;
      }
    }
    if constexpr(BCOL){ // stage B from [N][K] source
      const ushort* b = Bp + (long)(n0 + r)*ldb + k0 + cc;
      ushort* dst = &Bs[r][cc];
      *(s8v*)dst = *(const s8v*)b; *(s8v*)(dst+8) = *(const s8v*)(b+8);
    } else {            // stage B from [K][N] source, transpose into Bs[n][k]
      const ushort* b = Bp + (long)(k0 + r)*ldb + n0 + cc;
      s8v v0 = *(const s8v*)b, v1 = *(const s8v*)(b+8);
      #pragma unroll
      for(int i=0;i<8;i++){ Bs[cc+i][r]=(ushort)v0[i]; Bs[cc+8+i][r]=(ushort)v1[i]; }
    }
    __syncthreads();
    #pragma unroll
    for(int ks=0; ks<64; ks+=32){
      bf8 av = *(const bf8*)&As[(w<<4)+(l&15)][ks + ((l>>4)<<3)];
      #pragma unroll
      for(int nf=0; nf<4; nf++){
        bf8 bv = *(const bf8*)&Bs[(nf<<4)+(l&15)][ks + ((l>>4)<<3)];
        acc[nf] = __builtin_amdgcn_mfma_f32_16x16x32_bf16(av, bv, acc[nf], 0, 0, 0);
      }
    }
    __syncthreads();
  }
  #pragma unroll
  for(int nf=0; nf<4; nf++){
    const int col = n0 + (nf<<4) + (l&15);
    float bv = 0.f;
    if constexpr(HASB) bv = bias[col];
    #pragma unroll
    for(int j=0;j<4;j++){
      const int row = m0 + (w<<4) + ((l>>4)<<2) + j;
      if(row < M){
        float v = acc[nf][j] + bv;
        if constexpr(OBF16) ((ushort*)Cp)[sCz*z + (long)row*ldc + col] = f2bf(v);
        else ((float*)Cp)[sCz*z + (long)row*ldc + col] = v;
      }
    }
  }
}

// ---------------- per-step kernels ----------------

// flash attention partials: grid 256 = (batch b)*4 + s-chunk j (128 rows each)
__global__ __launch_bounds__(256) void k_attn(const ushort* __restrict__ esrc,
    const float* __restrict__ q, const int* __restrict__ smask,
    float* __restrict__ pm, float* __restrict__ pl, float* __restrict__ pc)
{
  const int b = blockIdx.x>>2, j = blockIdx.x&3;
  const int w = threadIdx.x>>6, l = threadIdx.x&63;
  __shared__ float ms[4], ls[4];
  __shared__ float ctxs[4][1024];
  float qr[16];
  {
    const float* qp = q + (b<<10) + l*16;
    #pragma unroll
    for(int i=0;i<16;i+=4){ float4 v=*(const float4*)(qp+i); qr[i]=v.x; qr[i+1]=v.y; qr[i+2]=v.z; qr[i+3]=v.w; }
  }
  float m = -3.4e38f, lsum = 0.f;
  float cacc[16];
  #pragma unroll
  for(int i=0;i<16;i++) cacc[i]=0.f;
  const int sbase = (j<<7) + w;
  for(int rr=0; rr<32; rr++){
    const int s = sbase + (rr<<2);
    const ushort* ep = esrc + (((long)((b<<9) + s))<<10) + l*16;
    s8v e0 = *(const s8v*)ep, e1 = *(const s8v*)(ep+8);
    float ef[16];
    #pragma unroll
    for(int i=0;i<8;i++){ ef[i]=bf2f((ushort)e0[i]); ef[8+i]=bf2f((ushort)e1[i]); }
    float d = 0.f;
    #pragma unroll
    for(int i=0;i<16;i++) d += ef[i]*qr[i];
    d = wred(d);
    if(smask[(b<<9)+s]==1) d += -1.0e9f;
    const float mn = fmaxf(m, d);
    const float sc = __expf(m - mn);
    const float p = __expf(d - mn);
    lsum = lsum*sc + p;
    #pragma unroll
    for(int i=0;i<16;i++) cacc[i] = cacc[i]*sc + p*ef[i];
    m = mn;
  }
  if(l==0){ ms[w]=m; ls[w]=lsum; }
  #pragma unroll
  for(int i=0;i<16;i++) ctxs[w][l*16+i]=cacc[i];
  __syncthreads();
  const float mb = fmaxf(fmaxf(ms[0],ms[1]),fmaxf(ms[2],ms[3]));
  const float w0=__expf(ms[0]-mb), w1=__expf(ms[1]-mb), w2=__expf(ms[2]-mb), w3=__expf(ms[3]-mb);
  const int jb = (j<<6) + b;
  for(int d0=threadIdx.x; d0<1024; d0+=256){
    pc[((long)jb<<10)+d0] = ctxs[0][d0]*w0 + ctxs[1][d0]*w1 + ctxs[2][d0]*w2 + ctxs[3][d0]*w3;
  }
  if(threadIdx.x==0){ pm[jb]=mb; pl[jb]=ls[0]*w0 + ls[1]*w1 + ls[2]*w2 + ls[3]*w3; }
}

// gates = combine(ctx partials)@W_ih2 + h@W_hh + gates_pre[t]; LSTM cell; 64 blocks
__global__ __launch_bounds__(256) void k_lstm(const float* __restrict__ pm,
    const float* __restrict__ pl, const float* __restrict__ pc,
    const float* __restrict__ hin, const float* __restrict__ cin,
    const ushort* __restrict__ Wcat, const ushort* __restrict__ gpre_t,
    float* __restrict__ hout, float* __restrict__ cout)
{
  __shared__ ushort As[64][72];
  __shared__ ushort Bs[64][72];
  __shared__ float wj[4][64];
  const int tid = threadIdx.x;
  const int w = tid>>6, l = tid&63;
  const int r = tid>>2, cc = (tid&3)<<4;
  const int jblk = blockIdx.x;
  if(tid < 64){
    float m0v=pm[tid], m1v=pm[64+tid], m2v=pm[128+tid], m3v=pm[192+tid];
    float mm = fmaxf(fmaxf(m0v,m1v),fmaxf(m2v,m3v));
    float e0=__expf(m0v-mm), e1=__expf(m1v-mm), e2=__expf(m2v-mm), e3=__expf(m3v-mm);
    float den = pl[tid]*e0 + pl[64+tid]*e1 + pl[128+tid]*e2 + pl[192+tid]*e3;
    float inv = 1.0f/den;
    wj[0][tid]=e0*inv; wj[1][tid]=e1*inv; wj[2][tid]=e2*inv; wj[3][tid]=e3*inv;
  }
  f4v acc[4];
  #pragma unroll
  for(int nf=0;nf<4;nf++){
    #pragma unroll
    for(int jj=0;jj<4;jj++){
      const int row = (w<<4) + ((l>>4)<<2) + jj;
      const int col = (nf<<10) + (jblk<<4) + (l&15);
      acc[nf][jj] = bf2f(gpre_t[((long)row<<12) + col]);
    }
  }
  __syncthreads();
  for(int k0=0; k0<2048; k0+=64){
    {
      ushort* dst = &As[r][cc];
      s8v o0, o1;
      if(k0 < 1024){
        const float a0=wj[0][r], a1=wj[1][r], a2=wj[2][r], a3=wj[3][r];
        const float* p0 = pc + ((long)r<<10) + k0 + cc;
        const float* p1 = p0 + 65536;
        const float* p2 = p0 + 131072;
        const float* p3 = p0 + 196608;
        #pragma unroll
        for(int i=0;i<16;i+=4){
          float4 v0=*(const float4*)(p0+i), v1=*(const float4*)(p1+i), v2=*(const float4*)(p2+i), v3=*(const float4*)(p3+i);
          float x0 = v0.x*a0+v1.x*a1+v2.x*a2+v3.x*a3;
          float x1 = v0.y*a0+v1.y*a1+v2.y*a2+v3.y*a3;
          float x2 = v0.z*a0+v1.z*a1+v2.z*a2+v3.z*a3;
          float x3 = v0.w*a0+v1.w*a1+v2.w*a2+v3.w*a3;
          if(i<8){ o0[i]=(short)f2bf(x0); o0[i+1]=(short)f2bf(x1); o0[i+2]=(short)f2bf(x2); o0[i+3]=(short)f2bf(x3); }
          else { o1[i-8]=(short)f2bf(x0); o1[i-7]=(short)f2bf(x1); o1[i-6]=(short)f2bf(x2); o1[i-5]=(short)f2bf(x3); }
        }
      } else {
        const float* hp = hin + ((long)r<<10) + (k0-1024) + cc;
        float4 v0=*(const float4*)(hp), v1=*(const float4*)(hp+4), v2=*(const float4*)(hp+8), v3=*(const float4*)(hp+12);
        o0[0]=(short)f2bf(v0.x); o0[1]=(short)f2bf(v0.y); o0[2]=(short)f2bf(v0.z); o0[3]=(short)f2bf(v0.w);
        o0[4]=(short)f2bf(v1.x); o0[5]=(short)f2bf(v1.y); o0[6]=(short)f2bf(v1.z); o0[7]=(short)f2bf(v1.w);
        o1[0]=(short)f2bf(v2.x); o1[1]=(short)f2bf(v2.y); o1[2]=(short)f2bf(v2.z); o1[3]=(short)f2bf(v2.w);
        o1[4]=(short)f2bf(v3.x); o1[5]=(short)f2bf(v3.y); o1[6]=(short)f2bf(v3.z); o1[7]=(short)f2bf(v3.w);
      }
      *(s8v*)dst = o0; *(s8v*)(dst+8) = o1;
    }
    {
      const int kk = r, g = tid&3;
      const ushort* bp = Wcat + ((long)(k0+kk)<<12) + (g<<10) + (jblk<<4);
      s8v v0 = *(const s8v*)bp, v1 = *(const s8v*)(bp+8);
      #pragma unroll
      for(int i=0;i<8;i++){ Bs[(g<<4)+i][kk]=(ushort)v0[i]; Bs[(g<<4)+8+i][kk]=(ushort)v1[i]; }
    }
    __syncthreads();
    #pragma unroll
    for(int ks=0; ks<64; ks+=32){
      bf8 av = *(const bf8*)&As[(w<<4)+(l&15)][ks+((l>>4)<<3)];
      #pragma unroll
      for(int nf=0;nf<4;nf++){
        bf8 bv = *(const bf8*)&Bs[(nf<<4)+(l&15)][ks+((l>>4)<<3)];
        acc[nf] = __builtin_amdgcn_mfma_f32_16x16x32_bf16(av, bv, acc[nf], 0, 0, 0);
      }
    }
    __syncthreads();
  }
  #pragma unroll
  for(int jj=0;jj<4;jj++){
    const int row = (w<<4) + ((l>>4)<<2) + jj;
    const int col = (jblk<<4) + (l&15);
    const float iv = acc[0][jj], fv = acc[1][jj], gv = acc[2][jj], ov = acc[3][jj];
    const float cold = cin[(row<<10)+col];
    const float c2 = sigm(fv)*cold + sigm(iv)*tanhf(gv);
    const float h2v = sigm(ov)*tanhf(c2);
    cout[(row<<10)+col] = c2;
    hout[(row<<10)+col] = h2v;
  }
}

// heads (blocks 0..191: (b, head)) + q for next step (blocks 192..207)
__global__ __launch_bounds__(256) void k_heads(const float* __restrict__ h2,
    const ushort* __restrict__ GAt, const ushort* __restrict__ GCt, const ushort* __restrict__ GTt,
    const float* __restrict__ ca, const float* __restrict__ cb, const float* __restrict__ ct,
    const int* __restrict__ gold, const int* __restrict__ kindv, const int t,
    float* __restrict__ loss, float* __restrict__ q, const ushort* __restrict__ Wtgt,
    const float* __restrict__ btgt)
{
  __shared__ ushort As[64][72];
  __shared__ ushort Bs[64][72];
  __shared__ float logits[128];
  const int tid = threadIdx.x, w = tid>>6, l = tid&63;
  const int bid = blockIdx.x;
  if(bid < 192){
    const int b = bid/3, head = bid - b*3;
    int R; const ushort* G; const float* cons;
    if(head==0){ R=128; G=GAt; cons=ca + (b<<7); }
    else if(head==1){ R=64; G=GCt + ((long)b<<16); cons=cb + (b<<6); }
    else { R=32; G=GTt + ((long)b<<15); cons=ct + (b<<5); }
    float hr[16];
    {
      const float* hp = h2 + ((long)b<<10) + l*16;
      #pragma unroll
      for(int i=0;i<16;i+=4){ float4 v=*(const float4*)(hp+i); hr[i]=v.x; hr[i+1]=v.y; hr[i+2]=v.z; hr[i+3]=v.w; }
    }
    for(int rr=w; rr<R; rr+=4){
      const ushort* gp = G + ((long)rr<<10) + l*16;
      s8v g0=*(const s8v*)gp, g1=*(const s8v*)(gp+8);
      float d = 0.f;
      #pragma unroll
      for(int i=0;i<8;i++){ d += bf2f((ushort)g0[i])*hr[i]; d += bf2f((ushort)g1[i])*hr[8+i]; }
      d = wred(d);
      if(l==0) logits[rr] = d + cons[rr];
    }
    __syncthreads();
    if(w==0){
      float mx = -3.4e38f;
      for(int idx=l; idx<R; idx+=64) mx = fmaxf(mx, logits[idx]);
      #pragma unroll
      for(int off=32; off; off>>=1) mx = fmaxf(mx, __shfl_xor(mx, off, 64));
      float s = 0.f;
      for(int idx=l; idx<R; idx+=64) s += __expf(logits[idx]-mx);
      s = wred(s);
      if(l==0){
        const float lse = mx + __logf(s);
        const int kd = kindv[(t<<6)+b];
        const bool mine = (head==0 && kd==0) || (head==1 && kd==1) || (head==2 && kd!=0 && kd!=1);
        if(mine){
          const int gi = gold[(t<<6)+b];
          const int gidx = gi & (R-1);
          loss[b] -= (logits[gidx] - lse);
        }
      }
    }
  } else {
    const int n0 = (bid-192)<<6;
    const int r = tid>>2, cc = (tid&3)<<4;
    f4v acc[4];
    #pragma unroll
    for(int i=0;i<4;i++) acc[i]=(f4v){0.f,0.f,0.f,0.f};
    for(int k0=0; k0<1024; k0+=64){
      {
        const float* a = h2 + ((long)r<<10) + k0 + cc;
        float4 v0=*(const float4*)(a), v1=*(const float4*)(a+4), v2=*(const float4*)(a+8), v3=*(const float4*)(a+12);
        s8v o0, o1;
        o0[0]=(short)f2bf(v0.x); o0[1]=(short)f2bf(v0.y); o0[2]=(short)f2bf(v0.z); o0[3]=(short)f2bf(v0.w);
        o0[4]=(short)f2bf(v1.x); o0[5]=(short)f2bf(v1.y); o0[6]=(short)f2bf(v1.z); o0[7]=(short)f2bf(v1.w);
        o1[0]=(short)f2bf(v2.x); o1[1]=(short)f2bf(v2.y); o1[2]=(short)f2bf(v2.z); o1[3]=(short)f2bf(v2.w);
        o1[4]=(short)f2bf(v3.x); o1[5]=(short)f2bf(v3.y); o1[6]=(short)f2bf(v3.z); o1[7]=(short)f2bf(v3.w);
        *(s8v*)&As[r][cc]=o0; *(s8v*)&As[r][cc+8]=o1;
      }
      {
        const ushort* bp = Wtgt + ((long)(k0+r)<<10) + n0 + cc;
        s8v v0=*(const s8v*)bp, v1=*(const s8v*)(bp+8);
        #pragma unroll
        for(int i=0;i<8;i++){ Bs[cc+i][r]=(ushort)v0[i]; Bs[cc+8+i][r]=(ushort)v1[i]; }
      }
      __syncthreads();
      #pragma unroll
      for(int ks=0; ks<64; ks+=32){
        bf8 av=*(const bf8*)&As[(w<<4)+(l&15)][ks+((l>>4)<<3)];
        #pragma unroll
        for(int nf=0;nf<4;nf++){
          bf8 bv=*(const bf8*)&Bs[(nf<<4)+(l&15)][ks+((l>>4)<<3)];
          acc[nf]=__builtin_amdgcn_mfma_f32_16x16x32_bf16(av,bv,acc[nf],0,0,0);
        }
      }
      __syncthreads();
    }
    #pragma unroll
    for(int nf=0;nf<4;nf++){
      const int col = n0 + (nf<<4) + (l&15);
      const float bv = btgt[col];
      #pragma unroll
      for(int jj=0;jj<4;jj++){
        const int row = (w<<4) + ((l>>4)<<2) + jj;
        q[(row<<10)+col] = acc[nf][jj] + bv;
      }
    }
  }
}

// ---------------- host ----------------

extern "C" void kernel_launch(void* const* d_in, const int* in_sizes, int n_in,
                              void* d_out, int out_size, void* d_ws, size_t ws_size,
                              hipStream_t stream)
{
  const float *e_src=(const float*)d_in[0], *e_col=(const float*)d_in[1], *e_tab=(const float*)d_in[2];
  const float *h0=(const float*)d_in[3], *c0=(const float*)d_in[4];
  const float *emba=(const float*)d_in[5], *embs=(const float*)d_in[6];
  const float *W_tgt=(const float*)d_in[7], *b_tgt=(const float*)d_in[8];
  const float *W_act=(const float*)d_in[9], *b_act=(const float*)d_in[10];
  const float *W_col=(const float*)d_in[11], *b_col=(const float*)d_in[12];
  const float *W_tab=(const float*)d_in[13], *b_tab=(const float*)d_in[14];
  const float *W_out=(const float*)d_in[15], *b_out=(const float*)d_in[16];
  const float *W_ih=(const float*)d_in[17], *b_ih=(const float*)d_in[18];
  const float *W_hh=(const float*)d_in[19], *b_hh=(const float*)d_in[20];
  const int *smask=(const int*)d_in[21], *cmask=(const int*)d_in[22], *tmask=(const int*)d_in[23];
  const int *amask=(const int*)d_in[24];
  const int *cur=(const int*)d_in[25], *kindp=(const int*)d_in[26], *goldp=(const int*)d_in[27];

  char* wp = (char*)d_ws;
  auto alloc = [&](size_t n)->char*{ char* p = wp; wp += (n + 255) & ~(size_t)255; return p; };
  ushort* esrc_bf = (ushort*)alloc(67108864);
  ushort* WihA    = (ushort*)alloc(16777216);
  ushort* Wcat    = (ushort*)alloc(16777216);
  ushort* Wtgtb   = (ushort*)alloc(2097152);
  ushort* Bcat    = (ushort*)alloc(6291456);
  float*  U       = (float*) alloc(12582912);
  ushort* Ubf     = (ushort*)alloc(6291456);
  ushort* GAt     = (ushort*)alloc(262144);
  ushort* GCt     = (ushort*)alloc(8388608);
  ushort* GTt     = (ushort*)alloc(4194304);
  ushort* P       = (ushort*)alloc(10485760);
  ushort* gpre    = (ushort*)alloc(20971520);
  float* biasvec  = (float*)alloc(16384);
  float* vv       = (float*)alloc(12288);
  float* dbuf     = (float*)alloc(25088);
  float* ca       = (float*)alloc(32768);
  float* cb       = (float*)alloc(16384);
  float* ctb      = (float*)alloc(8192);
  float* pm       = (float*)alloc(1024);
  float* pl       = (float*)alloc(1024);
  float* pc       = (float*)alloc(1048576);
  float* hb0      = (float*)alloc(262144);
  float* hb1      = (float*)alloc(262144);
  float* cb0      = (float*)alloc(262144);
  float* cb1      = (float*)alloc(262144);
  float* qb       = (float*)alloc(262144);
  float* out      = (float*)d_out;

  k_cast<<<4096,256,0,stream>>>(e_src, esrc_bf, 8388608L);
  k_cast<<<2048,256,0,stream>>>(W_ih, WihA, 2097152L);
  k_wcat<<<2048,256,0,stream>>>(W_ih, W_hh, Wcat);
  k_cast<<<512,256,0,stream>>>(W_tgt, Wtgtb, 262144L);
  k_bcat<<<1024,256,0,stream>>>(W_col, W_tab, W_act, Bcat);
  k_gatherP<<<2048,256,0,stream>>>(emba, e_col, e_tab, embs, kindp, goldp, cur, P);
  k_init<<<256,256,0,stream>>>(h0, c0, b_ih, b_hh, hb0, cb0, biasvec, out);

  { dim3 g(64,40,1);
    k_gemm<false,false,true,true><<<g,256,0,stream>>>(P, WihA, gpre, biasvec,
        2560,4096,2048, 2048,4096,4096, 0,0); }
  { dim3 g(48,16,1);
    k_gemm<true,false,false,false><<<g,256,0,stream>>>(W_out, Bcat, U, nullptr,
        1024,3072,1024, 1024,3072,3072, 0,0); }
  k_cast<<<1024,256,0,stream>>>(U, Ubf, 786432L);
  { dim3 g(16,2,1);
    k_gemm<true,true,true,false><<<g,256,0,stream>>>(emba, Ubf+2048, GAt, nullptr,
        128,1024,1024, 1024,3072,1024, 0,0); }
  { dim3 g(16,1,64);
    k_gemm<true,true,true,false><<<g,256,0,stream>>>(e_col, Ubf, GCt, nullptr,
        64,1024,1024, 1024,3072,1024, 65536,65536); }
  { dim3 g(16,1,64);
    k_gemm<true,true,true,false><<<g,256,0,stream>>>(e_tab, Ubf+1024, GTt, nullptr,
        32,1024,1024, 1024,3072,1024, 32768,32768); }
  k_bias1<<<12,256,0,stream>>>(b_out, W_act, b_act, W_col, b_col, W_tab, b_tab, vv);
  k_bias2a<<<1568,256,0,stream>>>(vv, emba, e_col, e_tab, dbuf);
  k_bias2b<<<56,256,0,stream>>>(dbuf, amask, cmask, tmask, ca, cb, ctb);
  { dim3 g(16,1,1);
    k_gemm<true,false,false,true><<<g,256,0,stream>>>(hb0, Wtgtb, qb, b_tgt,
        64,1024,1024, 1024,1024,1024, 0,0); }

  for(int t=0; t<40; t++){
    float* hin  = (t&1) ? hb1 : hb0;
    float* cin  = (t&1) ? cb1 : cb0;
    float* hout = (t&1) ? hb0 : hb1;
    float* cout = (t&1) ? cb0 : cb1;
    k_attn<<<256,256,0,stream>>>(esrc_bf, qb, smask, pm, pl, pc);
    k_lstm<<<64,256,0,stream>>>(pm, pl, pc, hin, cin, Wcat, gpre + (long)t*262144, hout, cout);
    k_heads<<<208,256,0,stream>>>(hout, GAt, GCt, GTt, ca, cb, ctb, goldp, kindp, t, out, qb, Wtgtb, b_tgt);
  }
}

// Round 2
// 2999.678 us; speedup vs baseline: 1.4894x; 1.4894x over previous
//
#include <hip/hip_runtime.h>
#include <math.h>

typedef short s8v __attribute__((ext_vector_type(8)));
typedef __bf16 bf8 __attribute__((ext_vector_type(8)));
typedef float f4v __attribute__((ext_vector_type(4)));

#define DEV static __device__ __forceinline__

DEV ushort f2bf(float f){
  union { float f; unsigned u; } v; v.f = f;
  unsigned u = v.u;
  return (ushort)((u + 0x7fffu + ((u>>16)&1u)) >> 16);
}
DEV float bf2f(ushort u){
  union { unsigned u; float f; } v; v.u = ((unsigned)u)<<16; return v.f;
}
DEV float sigm(float x){ return 1.0f/(1.0f + __expf(-x)); }
DEV float tanh_(float x){ float e=__expf(2.f*x); return 1.f - 2.f/(e+1.f); }
DEV float wred(float x){
  #pragma unroll
  for(int off=32; off; off>>=1) x += __shfl_xor(x, off, 64);
  return x;
}
// swizzled LDS index for a [64][64]-ushort tile; uscol must be 8-aligned at use sites
DEV int swz(int row, int uscol){
  return (row<<6) + ((((uscol>>3) ^ (row&7))<<3) | (uscol&7));
}

// ---------------- precompute kernels ----------------

__global__ void k_cast(const float* __restrict__ s, ushort* __restrict__ d, long n4){
  long i = (long)blockIdx.x*256 + threadIdx.x;
  const long st = (long)gridDim.x*256;
  for(; i<n4; i+=st){
    float4 v = ((const float4*)s)[i];
    ushort4 o; o.x=f2bf(v.x); o.y=f2bf(v.y); o.z=f2bf(v.z); o.w=f2bf(v.w);
    ((ushort4*)d)[i]=o;
  }
}

// transpose: src f32 [R][C] -> dst bf16 [C][ldd], dst[n][roff + k] = src[k][n]
__global__ __launch_bounds__(256) void k_tr(const float* __restrict__ src, int R, int C,
    ushort* __restrict__ dst, int ldd, int roff){
  __shared__ ushort T[64][72];
  const int tid = threadIdx.x;
  const int c0 = blockIdx.x<<6, r0 = blockIdx.y<<6;
  {
    const int rr = tid>>2, cc = (tid&3)<<4;
    const float* s = src + (long)(r0+rr)*C + c0 + cc;
    float4 v0=*(const float4*)(s), v1=*(const float4*)(s+4), v2=*(const float4*)(s+8), v3=*(const float4*)(s+12);
    ushort* t = &T[rr][cc];
    t[0]=f2bf(v0.x); t[1]=f2bf(v0.y); t[2]=f2bf(v0.z); t[3]=f2bf(v0.w);
    t[4]=f2bf(v1.x); t[5]=f2bf(v1.y); t[6]=f2bf(v1.z); t[7]=f2bf(v1.w);
    t[8]=f2bf(v2.x); t[9]=f2bf(v2.y); t[10]=f2bf(v2.z); t[11]=f2bf(v2.w);
    t[12]=f2bf(v3.x); t[13]=f2bf(v3.y); t[14]=f2bf(v3.z); t[15]=f2bf(v3.w);
  }
  __syncthreads();
  {
    const int rr = tid>>2, cc = (tid&3)<<4;
    s8v o0, o1;
    #pragma unroll
    for(int i=0;i<8;i++){ o0[i]=(short)T[cc+i][rr]; o1[i]=(short)T[cc+8+i][rr]; }
    ushort* dp = dst + (long)(c0+rr)*ldd + roff + r0 + cc;
    *(s8v*)dp = o0; *(s8v*)(dp+8) = o1;
  }
}

// P[2560][2048] bf16: cols 0:1024 = prev_emb(t), cols 1024:2048 = node_emb(t)
__global__ void k_gatherP(const float* __restrict__ emba, const float* __restrict__ ecol,
                          const float* __restrict__ etab, const float* __restrict__ symb,
                          const int* __restrict__ kindv, const int* __restrict__ gold,
                          const int* __restrict__ cur, ushort* __restrict__ P){
  long i = (long)blockIdx.x*256 + threadIdx.x;
  const long st = (long)gridDim.x*256;
  const long n4 = 2560L*2048/4;
  for(; i<n4; i+=st){
    long pos = i*4; int row = (int)(pos>>11); int col = (int)(pos&2047);
    int t = row>>6, b = row&63;
    ushort4 o;
    if(col < 1024){
      if(t==0){ o.x=o.y=o.z=o.w=0; *(ushort4*)&P[pos]=o; continue; }
      int k = kindv[(t-1)*64+b];
      int gi = gold[(t-1)*64+b];
      const float* s;
      if(k==0) s = emba + ((long)(gi & 127))*1024 + col;
      else if(k==1) s = ecol + (((long)b<<6) + (gi & 63))*1024 + col;
      else s = etab + (((long)b<<5) + (gi & 31))*1024 + col;
      float4 v = *(const float4*)s;
      o.x=f2bf(v.x); o.y=f2bf(v.y); o.z=f2bf(v.z); o.w=f2bf(v.w);
    } else {
      const float* s = symb + ((long)cur[t*64+b])*1024 + (col-1024);
      float4 v = *(const float4*)s;
      o.x=f2bf(v.x); o.y=f2bf(v.y); o.z=f2bf(v.z); o.w=f2bf(v.w);
    }
    *(ushort4*)&P[pos] = o;
  }
}

__global__ void k_init(const float* __restrict__ h0, const float* __restrict__ c0,
                       const float* __restrict__ bih, const float* __restrict__ bhh,
                       float* __restrict__ cbuf, ushort* __restrict__ Ab0,
                       float* __restrict__ biasvec){
  int i = blockIdx.x*256 + threadIdx.x;
  if(i < 65536){
    cbuf[i]=c0[i];
    int row=i>>10, col=i&1023;
    Ab0[(row<<11)+1024+col]=f2bf(h0[i]);
  }
  if(i < 4096) biasvec[i] = bih[i] + bhh[i];
}

// vv[3][1024]: b_out@W_act+b_act, b_out@W_col+b_col, b_out@W_tab+b_tab
__global__ void k_bias1(const float* __restrict__ bout,
                        const float* __restrict__ Wa, const float* __restrict__ ba,
                        const float* __restrict__ Wc, const float* __restrict__ bc,
                        const float* __restrict__ Wt, const float* __restrict__ bt,
                        float* __restrict__ vv){
  int j = blockIdx.x*256 + threadIdx.x;
  if(j >= 3072) return;
  int which = j>>10, col = j&1023;
  const float* W = (which==0)?Wa:(which==1)?Wc:Wt;
  const float* bb = (which==0)?ba:(which==1)?bc:bt;
  float s = bb[col];
  for(int i=0;i<1024;i++) s += bout[i]*W[((long)i<<10)+col];
  vv[j] = s;
}

__global__ void k_bias2a(const float* __restrict__ vv, const float* __restrict__ emb,
                         const float* __restrict__ ecol, const float* __restrict__ etab,
                         float* __restrict__ dbuf){
  int wid = blockIdx.x*4 + (threadIdx.x>>6);
  int l = threadIdx.x & 63;
  if(wid >= 6272) return;
  const float* src; const float* v;
  if(wid < 128){ src = emb + ((long)wid<<10); v = vv; }
  else if(wid < 4224){ src = ecol + ((long)(wid-128)<<10); v = vv+1024; }
  else { src = etab + ((long)(wid-4224)<<10); v = vv+2048; }
  const float* sp = src + l*16; const float* vp = v + l*16;
  float s = 0.f;
  #pragma unroll
  for(int i=0;i<16;i+=4){
    float4 a = *(const float4*)(sp+i); float4 bvv = *(const float4*)(vp+i);
    s += a.x*bvv.x + a.y*bvv.y + a.z*bvv.z + a.w*bvv.w;
  }
  s = wred(s);
  if(l==0) dbuf[wid] = s;
}

__global__ void k_bias2b(const float* __restrict__ dbuf,
                         const int* __restrict__ amask, const int* __restrict__ cmask,
                         const int* __restrict__ tmask,
                         float* __restrict__ ca, float* __restrict__ cb, float* __restrict__ ct){
  int i = blockIdx.x*256 + threadIdx.x;
  if(i < 8192){ ca[i] = dbuf[i&127] + ((amask[i]==1)?-1.0e9f:0.f); }
  else if(i < 12288){ int j=i-8192; cb[j] = dbuf[128+j] + ((cmask[j]==1)?-1.0e9f:0.f); }
  else if(i < 14336){ int j=i-12288; ct[j] = dbuf[4224+j] + ((tmask[j]==1)?-1.0e9f:0.f); }
}

// ---------------- pipelined, swizzled bf16 MFMA GEMM ----------------
// C[M,N] = A[M,K] @ B[K,N] (+bias).  B stored column-form: B[k][n] = Bp[n*ldb + k].
template<bool AF32, bool OBF16, bool HASB>
__global__ __launch_bounds__(256) void k_gemm(const void* __restrict__ Ap,
    const ushort* __restrict__ Bp, void* __restrict__ Cp, const float* __restrict__ bias,
    int M, int N, int K, int lda, int ldb, int ldc, long sAz, long sCz)
{
  __shared__ __align__(16) ushort As[4096];
  __shared__ __align__(16) ushort Bs[4096];
  const int tid=threadIdx.x, w=tid>>6, l=tid&63, g=l>>4;
  const int r=tid>>2, cc=(tid&3)<<4;
  const int m0=blockIdx.y<<6, n0=blockIdx.x<<6;
  const int z=blockIdx.z;
  f4v acc[4];
  #pragma unroll
  for(int i=0;i<4;i++) acc[i]=(f4v){0.f,0.f,0.f,0.f};

  float4 ra0,ra1,ra2,ra3;
  s8v rab0, rab1, rb0, rb1;

  auto loadA = [&](int k0){
    const int gm = m0 + r;
    if constexpr(AF32){
      if(gm < M){
        const float* a = (const float*)Ap + sAz*z + (long)gm*lda + k0 + cc;
        ra0=*(const float4*)(a); ra1=*(const float4*)(a+4); ra2=*(const float4*)(a+8); ra3=*(const float4*)(a+12);
      } else { ra0=ra1=ra2=ra3=make_float4(0.f,0.f,0.f,0.f); }
    } else {
      if(gm < M){
        const ushort* a = (const ushort*)Ap + sAz*z + (long)gm*lda + k0 + cc;
        rab0=*(const s8v*)a; rab1=*(const s8v*)(a+8);
      } else { rab0=rab1=(s8v){0,0,0,0,0,0,0,0}; }
    }
  };
  auto loadB = [&](int k0){
    const ushort* b = Bp + (long)(n0+r)*ldb + k0 + cc;
    rb0=*(const s8v*)b; rb1=*(const s8v*)(b+8);
  };
  auto stage = [&](){
    s8v a0, a1;
    if constexpr(AF32){
      a0[0]=(short)f2bf(ra0.x); a0[1]=(short)f2bf(ra0.y); a0[2]=(short)f2bf(ra0.z); a0[3]=(short)f2bf(ra0.w);
      a0[4]=(short)f2bf(ra1.x); a0[5]=(short)f2bf(ra1.y); a0[6]=(short)f2bf(ra1.z); a0[7]=(short)f2bf(ra1.w);
      a1[0]=(short)f2bf(ra2.x); a1[1]=(short)f2bf(ra2.y); a1[2]=(short)f2bf(ra2.z); a1[3]=(short)f2bf(ra2.w);
      a1[4]=(short)f2bf(ra3.x); a1[5]=(short)f2bf(ra3.y); a1[6]=(short)f2bf(ra3.z); a1[7]=(short)f2bf(ra3.w);
    } else { a0=rab0; a1=rab1; }
    *(s8v*)&As[swz(r,cc)] = a0; *(s8v*)&As[swz(r,cc+8)] = a1;
    *(s8v*)&Bs[swz(r,cc)] = rb0; *(s8v*)&Bs[swz(r,cc+8)] = rb1;
  };

  loadA(0); loadB(0);
  for(int k0=0;;){
    stage();
    __syncthreads();
    const int kn = k0 + 64;
    if(kn < K){ loadA(kn); loadB(kn); }
    #pragma unroll
    for(int ks=0; ks<64; ks+=32){
      bf8 av = *(const bf8*)&As[swz((w<<4)+(l&15), ks+(g<<3))];
      #pragma unroll
      for(int nf=0; nf<4; nf++){
        bf8 bv = *(const bf8*)&Bs[swz((nf<<4)+(l&15), ks+(g<<3))];
        acc[nf] = __builtin_amdgcn_mfma_f32_16x16x32_bf16(av, bv, acc[nf], 0, 0, 0);
      }
    }
    __syncthreads();
    if(kn >= K) break;
    k0 = kn;
  }
  #pragma unroll
  for(int nf=0; nf<4; nf++){
    const int col = n0 + (nf<<4) + (l&15);
    float bv = 0.f;
    if constexpr(HASB) bv = bias[col];
    #pragma unroll
    for(int j=0;j<4;j++){
      const int row = m0 + (w<<4) + ((l>>4)<<2) + j;
      if(row < M){
        float v = acc[nf][j] + bv;
        if constexpr(OBF16) ((ushort*)Cp)[sCz*z + (long)row*ldc + col] = f2bf(v);
        else ((float*)Cp)[sCz*z + (long)row*ldc + col] = v;
      }
    }
  }
}

// ---------------- per-step kernels ----------------

// flash attention partials: grid 512 = (batch b)*8 + s-chunk j (64 rows each)
__global__ __launch_bounds__(256) void k_attn(const ushort* __restrict__ esrc,
    const float* __restrict__ q, const int* __restrict__ smask,
    float* __restrict__ pm, float* __restrict__ pl, float* __restrict__ pc)
{
  const int b = blockIdx.x>>3, j = blockIdx.x&7;
  const int w = threadIdx.x>>6, l = threadIdx.x&63;
  __shared__ float ms[4], ls[4];
  __shared__ float ctxs[4][1024];
  float qr[16];
  {
    const float* qp = q + (b<<10) + l*16;
    #pragma unroll
    for(int i=0;i<16;i+=4){ float4 v=*(const float4*)(qp+i); qr[i]=v.x; qr[i+1]=v.y; qr[i+2]=v.z; qr[i+3]=v.w; }
  }
  float m = -3.4e38f, lsum = 0.f;
  float cacc[16];
  #pragma unroll
  for(int i=0;i<16;i++) cacc[i]=0.f;
  const int sbase = (j<<6) + w;
  for(int rr=0; rr<16; rr++){
    const int s = sbase + (rr<<2);
    const ushort* ep = esrc + (((long)((b<<9) + s))<<10) + l*16;
    s8v e0 = *(const s8v*)ep, e1 = *(const s8v*)(ep+8);
    float ef[16];
    #pragma unroll
    for(int i=0;i<8;i++){ ef[i]=bf2f((ushort)e0[i]); ef[8+i]=bf2f((ushort)e1[i]); }
    float d = 0.f;
    #pragma unroll
    for(int i=0;i<16;i++) d += ef[i]*qr[i];
    d = wred(d);
    if(smask[(b<<9)+s]==1) d += -1.0e9f;
    const float mn = fmaxf(m, d);
    const float sc = __expf(m - mn);
    const float p = __expf(d - mn);
    lsum = lsum*sc + p;
    #pragma unroll
    for(int i=0;i<16;i++) cacc[i] = cacc[i]*sc + p*ef[i];
    m = mn;
  }
  if(l==0){ ms[w]=m; ls[w]=lsum; }
  #pragma unroll
  for(int i=0;i<16;i++) ctxs[w][l*16+i]=cacc[i];
  __syncthreads();
  const float mb = fmaxf(fmaxf(ms[0],ms[1]),fmaxf(ms[2],ms[3]));
  const float w0=__expf(ms[0]-mb), w1=__expf(ms[1]-mb), w2=__expf(ms[2]-mb), w3=__expf(ms[3]-mb);
  const int jb = (j<<6) + b;
  for(int d0=threadIdx.x; d0<1024; d0+=256){
    pc[((long)jb<<10)+d0] = ctxs[0][d0]*w0 + ctxs[1][d0]*w1 + ctxs[2][d0]*w2 + ctxs[3][d0]*w3;
  }
  if(threadIdx.x==0){ pm[jb]=mb; pl[jb]=ls[0]*w0 + ls[1]*w1 + ls[2]*w2 + ls[3]*w3; }
}

// combine 8 attn partials -> ctx bf16 into Abuf cols 0:1024
__global__ __launch_bounds__(256) void k_combine(const float* __restrict__ pm,
    const float* __restrict__ pl, const float* __restrict__ pc, ushort* __restrict__ Ab)
{
  const int idx = blockIdx.x*256 + threadIdx.x;   // 0..8191
  const int b = idx>>7, c0 = (idx&127)<<3;
  float mv[8];
  #pragma unroll
  for(int j=0;j<8;j++) mv[j] = pm[(j<<6)+b];
  float M = mv[0];
  #pragma unroll
  for(int j=1;j<8;j++) M = fmaxf(M, mv[j]);
  float e[8]; float den = 0.f;
  #pragma unroll
  for(int j=0;j<8;j++){ e[j] = __expf(mv[j]-M); den += pl[(j<<6)+b]*e[j]; }
  const float inv = 1.f/den;
  float s0=0,s1=0,s2=0,s3=0,s4=0,s5=0,s6=0,s7=0;
  #pragma unroll
  for(int j=0;j<8;j++){
    const float wj = e[j]*inv;
    const float* p = pc + (((long)((j<<6)+b))<<10) + c0;
    float4 v0=*(const float4*)p, v1=*(const float4*)(p+4);
    s0+=wj*v0.x; s1+=wj*v0.y; s2+=wj*v0.z; s3+=wj*v0.w;
    s4+=wj*v1.x; s5+=wj*v1.y; s6+=wj*v1.z; s7+=wj*v1.w;
  }
  s8v o;
  o[0]=(short)f2bf(s0); o[1]=(short)f2bf(s1); o[2]=(short)f2bf(s2); o[3]=(short)f2bf(s3);
  o[4]=(short)f2bf(s4); o[5]=(short)f2bf(s5); o[6]=(short)f2bf(s6); o[7]=(short)f2bf(s7);
  *(s8v*)&Ab[(b<<11)+c0] = o;
}

// gates GEMM (A=[ctx|h] bf16 [64][2048], B=WcatT [4096][2048]) + LSTM cell; 64 blocks
__global__ __launch_bounds__(256) void k_lstm(const ushort* __restrict__ Abuf,
    const float* __restrict__ cin, const ushort* __restrict__ WcatT,
    const ushort* __restrict__ gpre_t, float* __restrict__ cout,
    ushort* __restrict__ AbOut, ushort* __restrict__ h2t)
{
  __shared__ __align__(16) ushort As[4096];
  __shared__ __align__(16) ushort Bs[4096];
  const int tid=threadIdx.x, w=tid>>6, l=tid&63, g=l>>4;
  const int r=tid>>2, cc=(tid&3)<<4;
  const int jblk = blockIdx.x;
  f4v acc[4];
  #pragma unroll
  for(int nf=0;nf<4;nf++){
    #pragma unroll
    for(int jj=0;jj<4;jj++){
      const int row = (w<<4) + ((l>>4)<<2) + jj;
      const int col = (nf<<10) + (jblk<<4) + (l&15);
      acc[nf][jj] = bf2f(gpre_t[((long)row<<12) + col]);
    }
  }
  s8v raA0, raA1, raB0, raB1;
  auto loadA = [&](int k0){
    const ushort* a = Abuf + ((long)r<<11) + k0 + cc;
    raA0=*(const s8v*)a; raA1=*(const s8v*)(a+8);
  };
  auto loadB = [&](int k0){
    const int nglob = ((r>>4)<<10) + (jblk<<4) + (r&15);
    const ushort* bp = WcatT + ((long)nglob<<11) + k0 + cc;
    raB0=*(const s8v*)bp; raB1=*(const s8v*)(bp+8);
  };
  loadA(0); loadB(0);
  for(int k0=0;;){
    *(s8v*)&As[swz(r,cc)] = raA0; *(s8v*)&As[swz(r,cc+8)] = raA1;
    *(s8v*)&Bs[swz(r,cc)] = raB0; *(s8v*)&Bs[swz(r,cc+8)] = raB1;
    __syncthreads();
    const int kn = k0 + 64;
    if(kn < 2048){ loadA(kn); loadB(kn); }
    #pragma unroll
    for(int ks=0; ks<64; ks+=32){
      bf8 av = *(const bf8*)&As[swz((w<<4)+(l&15), ks+(g<<3))];
      #pragma unroll
      for(int nf=0;nf<4;nf++){
        bf8 bv = *(const bf8*)&Bs[swz((nf<<4)+(l&15), ks+(g<<3))];
        acc[nf] = __builtin_amdgcn_mfma_f32_16x16x32_bf16(av, bv, acc[nf], 0, 0, 0);
      }
    }
    __syncthreads();
    if(kn >= 2048) break;
    k0 = kn;
  }
  #pragma unroll
  for(int jj=0;jj<4;jj++){
    const int row = (w<<4) + ((l>>4)<<2) + jj;
    const int col = (jblk<<4) + (l&15);
    const float iv = acc[0][jj], fv = acc[1][jj], gv = acc[2][jj], ov = acc[3][jj];
    const float cold = cin[(row<<10)+col];
    const float c2 = sigm(fv)*cold + sigm(iv)*tanh_(gv);
    const float h2v = sigm(ov)*tanh_(c2);
    cout[(row<<10)+col] = c2;
    const ushort hb = f2bf(h2v);
    AbOut[(row<<11) + 1024 + col] = hb;
    h2t[(row<<10)+col] = hb;
  }
}

// batched loss heads over all 40 steps: grid 7680 = t*192 + b*3 + head
__global__ __launch_bounds__(256) void k_loss(const ushort* __restrict__ h2a,
    const ushort* __restrict__ GAt, const ushort* __restrict__ GCt, const ushort* __restrict__ GTt,
    const float* __restrict__ ca, const float* __restrict__ cb, const float* __restrict__ ct,
    const int* __restrict__ gold, const int* __restrict__ kindv, float* __restrict__ lossbuf)
{
  const int blk = blockIdx.x;
  const int t = blk/192, rem = blk - t*192;
  const int b = rem/3, head = rem - b*3;
  const int tid = threadIdx.x, w = tid>>6, l = tid&63;
  __shared__ float logits[128];
  int R; const ushort* G; const float* cons;
  if(head==0){ R=128; G=GAt; cons=ca + (b<<7); }
  else if(head==1){ R=64; G=GCt + ((long)b<<16); cons=cb + (b<<6); }
  else { R=32; G=GTt + ((long)b<<15); cons=ct + (b<<5); }
  float hr[16];
  {
    const ushort* hp = h2a + (((long)((t<<6)+b))<<10) + l*16;
    s8v h0v=*(const s8v*)hp, h1v=*(const s8v*)(hp+8);
    #pragma unroll
    for(int i=0;i<8;i++){ hr[i]=bf2f((ushort)h0v[i]); hr[8+i]=bf2f((ushort)h1v[i]); }
  }
  for(int rr=w; rr<R; rr+=4){
    const ushort* gp = G + ((long)rr<<10) + l*16;
    s8v g0=*(const s8v*)gp, g1=*(const s8v*)(gp+8);
    float d = 0.f;
    #pragma unroll
    for(int i=0;i<8;i++){ d += bf2f((ushort)g0[i])*hr[i]; d += bf2f((ushort)g1[i])*hr[8+i]; }
    d = wred(d);
    if(l==0) logits[rr] = d + cons[rr];
  }
  __syncthreads();
  if(w==0){
    float mx = -3.4e38f;
    for(int idx=l; idx<R; idx+=64) mx = fmaxf(mx, logits[idx]);
    #pragma unroll
    for(int off=32; off; off>>=1) mx = fmaxf(mx, __shfl_xor(mx, off, 64));
    float s = 0.f;
    for(int idx=l; idx<R; idx+=64) s += __expf(logits[idx]-mx);
    s = wred(s);
    if(l==0){
      const float lse = mx + __logf(s);
      const int kd = kindv[(t<<6)+b];
      const bool mine = (head==0 && kd==0) || (head==1 && kd==1) || (head==2 && kd>=2);
      if(mine){
        const int gi = gold[(t<<6)+b];
        lossbuf[(t<<6)+b] = logits[gi & (R-1)] - lse;
      }
    }
  }
}

__global__ void k_loss_fin(const float* __restrict__ lossbuf, float* __restrict__ out){
  int b = threadIdx.x;
  if(b < 64){
    float s = 0.f;
    for(int t=0;t<40;t++) s += lossbuf[(t<<6)+b];
    out[b] = -s;
  }
}

// ---------------- host ----------------

extern "C" void kernel_launch(void* const* d_in, const int* in_sizes, int n_in,
                              void* d_out, int out_size, void* d_ws, size_t ws_size,
                              hipStream_t stream)
{
  const float *e_src=(const float*)d_in[0], *e_col=(const float*)d_in[1], *e_tab=(const float*)d_in[2];
  const float *h0=(const float*)d_in[3], *c0=(const float*)d_in[4];
  const float *emba=(const float*)d_in[5], *embs=(const float*)d_in[6];
  const float *W_tgt=(const float*)d_in[7], *b_tgt=(const float*)d_in[8];
  const float *W_act=(const float*)d_in[9], *b_act=(const float*)d_in[10];
  const float *W_col=(const float*)d_in[11], *b_col=(const float*)d_in[12];
  const float *W_tab=(const float*)d_in[13], *b_tab=(const float*)d_in[14];
  const float *W_out=(const float*)d_in[15], *b_out=(const float*)d_in[16];
  const float *W_ih=(const float*)d_in[17], *b_ih=(const float*)d_in[18];
  const float *W_hh=(const float*)d_in[19], *b_hh=(const float*)d_in[20];
  const int *smask=(const int*)d_in[21], *cmask=(const int*)d_in[22], *tmask=(const int*)d_in[23];
  const int *amask=(const int*)d_in[24];
  const int *cur=(const int*)d_in[25], *kindp=(const int*)d_in[26], *goldp=(const int*)d_in[27];

  char* wp = (char*)d_ws;
  auto alloc = [&](size_t n)->char*{ char* p = wp; wp += (n + 255) & ~(size_t)255; return p; };
  ushort* esrc_bf = (ushort*)alloc(67108864);
  ushort* WihT    = (ushort*)alloc(16777216);
  ushort* WcatT   = (ushort*)alloc(16777216);
  ushort* WtgtT   = (ushort*)alloc(2097152);
  ushort* BcatT   = (ushort*)alloc(6291456);
  float*  U       = (float*) alloc(12582912);   // aliased later by P
  ushort* Ubf     = (ushort*)alloc(6291456);
  ushort* GAt     = (ushort*)alloc(262144);
  ushort* GCt     = (ushort*)alloc(8388608);
  ushort* GTt     = (ushort*)alloc(4194304);
  ushort* gpre    = (ushort*)alloc(20971520);
  float* biasvec  = (float*)alloc(16384);
  float* vv       = (float*)alloc(12288);
  float* dbuf     = (float*)alloc(25088);
  float* ca       = (float*)alloc(32768);
  float* cb       = (float*)alloc(16384);
  float* ctb      = (float*)alloc(8192);
  float* pm       = (float*)alloc(2048);
  float* pl       = (float*)alloc(2048);
  float* pc       = (float*)alloc(2097152);
  ushort* Ab0     = (ushort*)alloc(262144);
  ushort* Ab1     = (ushort*)alloc(262144);
  float* cbuf0    = (float*)alloc(262144);
  float* cbuf1    = (float*)alloc(262144);
  float* qb       = (float*)alloc(262144);
  ushort* h2a     = (ushort*)alloc(5242880);
  float* lossbuf  = (float*)alloc(10240);
  ushort* P       = (ushort*)U;                 // alias: P used after U is consumed
  float* out      = (float*)d_out;

  k_cast<<<4096,256,0,stream>>>(e_src, esrc_bf, 8388608L);
  { dim3 g(64,32); k_tr<<<g,256,0,stream>>>(W_ih, 2048, 4096, WihT, 2048, 0); }
  { dim3 g(64,16); k_tr<<<g,256,0,stream>>>(W_ih + 2048L*4096, 1024, 4096, WcatT, 2048, 0); }
  { dim3 g(64,16); k_tr<<<g,256,0,stream>>>(W_hh, 1024, 4096, WcatT, 2048, 1024); }
  { dim3 g(16,16); k_tr<<<g,256,0,stream>>>(W_tgt, 1024, 1024, WtgtT, 1024, 0); }
  { dim3 g(16,16); k_tr<<<g,256,0,stream>>>(W_col, 1024, 1024, BcatT, 1024, 0); }
  { dim3 g(16,16); k_tr<<<g,256,0,stream>>>(W_tab, 1024, 1024, BcatT + 1048576, 1024, 0); }
  { dim3 g(16,16); k_tr<<<g,256,0,stream>>>(W_act, 1024, 1024, BcatT + 2097152, 1024, 0); }
  k_init<<<256,256,0,stream>>>(h0, c0, b_ih, b_hh, cbuf0, Ab0, biasvec);

  { dim3 g(48,16); k_gemm<true,false,false><<<g,256,0,stream>>>(W_out, BcatT, U, nullptr,
        1024,3072,1024, 1024,1024,3072, 0,0); }
  k_cast<<<1024,256,0,stream>>>(U, Ubf, 786432L);
  { dim3 g(16,2); k_gemm<true,true,false><<<g,256,0,stream>>>(emba, Ubf+2048, GAt, nullptr,
        128,1024,1024, 1024,3072,1024, 0,0); }
  { dim3 g(16,1,64); k_gemm<true,true,false><<<g,256,0,stream>>>(e_col, Ubf, GCt, nullptr,
        64,1024,1024, 1024,3072,1024, 65536,65536); }
  { dim3 g(16,1,64); k_gemm<true,true,false><<<g,256,0,stream>>>(e_tab, Ubf+1024, GTt, nullptr,
        32,1024,1024, 1024,3072,1024, 32768,32768); }
  k_bias1<<<12,256,0,stream>>>(b_out, W_act, b_act, W_col, b_col, W_tab, b_tab, vv);
  k_bias2a<<<1568,256,0,stream>>>(vv, emba, e_col, e_tab, dbuf);
  k_bias2b<<<56,256,0,stream>>>(dbuf, amask, cmask, tmask, ca, cb, ctb);

  k_gatherP<<<2048,256,0,stream>>>(emba, e_col, e_tab, embs, kindp, goldp, cur, P);
  { dim3 g(64,40); k_gemm<false,true,true><<<g,256,0,stream>>>(P, WihT, gpre, biasvec,
        2560,4096,2048, 2048,2048,4096, 0,0); }
  { dim3 g(16,1); k_gemm<true,false,true><<<g,256,0,stream>>>(h0, WtgtT, qb, b_tgt,
        64,1024,1024, 1024,1024,1024, 0,0); }

  for(int t=0; t<40; t++){
    ushort* Ain  = (t&1) ? Ab1 : Ab0;
    ushort* Aout = (t&1) ? Ab0 : Ab1;
    float* ci = (t&1) ? cbuf1 : cbuf0;
    float* co = (t&1) ? cbuf0 : cbuf1;
    k_attn<<<512,256,0,stream>>>(esrc_bf, qb, smask, pm, pl, pc);
    k_combine<<<32,256,0,stream>>>(pm, pl, pc, Ain);
    k_lstm<<<64,256,0,stream>>>(Ain, ci, WcatT, gpre + (long)t*262144, co, Aout, h2a + (long)t*65536);
    { dim3 g(16,1); k_gemm<false,false,true><<<g,256,0,stream>>>(Aout + 1024, WtgtT, qb, b_tgt,
          64,1024,1024, 2048,1024,1024, 0,0); }
  }
  k_loss<<<7680,256,0,stream>>>(h2a, GAt, GCt, GTt, ca, cb, ctb, goldp, kindp, lossbuf);
  k_loss_fin<<<1,64,0,stream>>>(lossbuf, out);
}